// Round 2
// baseline (144.236 us; speedup 1.0000x reference)
//
#include <hip/hip_runtime.h>

// GSKAN layer: out[b,q] = sum_p prelu(x[b,p] + eps[q]) * Lam[p,q]
// prelu(s) = c1*s + c2*|s|,  c1 = (1+a)/2, c2 = (1-a)/2  (|s| = free VOP3 modifier)
//
// Main kernel: 256 threads, output tile 128(b) x 64(q), 8x4 per thread.
// Per 4-p step per wave: 384 VALU instr vs 12 ds_read_b128 -> VALU-bound, LDS at 75%.
// p dimension split across blockIdx.z into partials; deterministic combine after.

#define PCHUNK 32

__global__ __launch_bounds__(256) void gskan_partial_kernel(
    const float* __restrict__ X,     // [B][n_in]
    const float* __restrict__ Lam,   // [n_in][n_out]
    const float* __restrict__ Eps,   // [n_out]
    const float* __restrict__ Aw,    // [1]
    float* __restrict__ Part,        // [nsplit][B][n_out]
    int B, int n_in, int n_out, int p_per_split)
{
    // X tile: [row][pg] with pg XOR-swizzled by (row>>3)&3 so the 4 rows read
    // simultaneously (8 apart within a wave) hit 16 distinct banks, not 4.
    __shared__ float xs[128 * PCHUNK];   // 16 KB
    __shared__ float ls[PCHUNK * 64];    // 8 KB, [p][q], row stride 256B

    const int tid = threadIdx.x;
    const int qg  = tid & 15;   // 16 q-groups of 4
    const int bl  = tid >> 4;   // 16 b-groups of 8

    const int q0 = blockIdx.x * 64;
    const int b0 = blockIdx.y * 128;
    const int p_begin = blockIdx.z * p_per_split;
    int p_end = p_begin + p_per_split;
    if (p_end > n_in) p_end = n_in;

    const float a  = Aw[0];
    const float c1 = 0.5f * (1.0f + a);
    const float c2 = 0.5f * (1.0f - a);

    const int q = q0 + qg * 4;
    const float4 ev = *reinterpret_cast<const float4*>(Eps + q);
    const float ee[4] = {ev.x, ev.y, ev.z, ev.w};

    float acc1[8][4] = {};
    float acc2[8][4] = {};

    for (int pc = p_begin; pc < p_end; pc += PCHUNK) {
        // stage X: 128 rows x 32 p = 4096 floats, 4 float4 per thread, coalesced reads
        #pragma unroll
        for (int r = 0; r < 4; ++r) {
            int slot = r * 256 + tid;        // 0..1023
            int row  = slot >> 3;            // 0..127
            int pg   = slot & 7;             // 0..7
            float4 v = *reinterpret_cast<const float4*>(
                X + (size_t)(b0 + row) * n_in + pc + pg * 4);
            int spg = pg ^ ((row >> 3) & 3);
            *reinterpret_cast<float4*>(&xs[row * PCHUNK + spg * 4]) = v;
        }
        // stage Lam: 32 p x 64 q = 2048 floats, 2 float4 per thread
        #pragma unroll
        for (int r = 0; r < 2; ++r) {
            int slot = r * 256 + tid;        // 0..511
            int row  = slot >> 4;            // 0..31
            int c4   = slot & 15;
            float4 v = *reinterpret_cast<const float4*>(
                Lam + (size_t)(pc + row) * n_out + q0 + c4 * 4);
            *reinterpret_cast<float4*>(&ls[row * 64 + c4 * 4]) = v;
        }
        __syncthreads();

        #pragma unroll
        for (int p = 0; p < PCHUNK; p += 4) {
            float4 lv[4];
            #pragma unroll
            for (int pp = 0; pp < 4; ++pp)
                lv[pp] = *reinterpret_cast<const float4*>(&ls[(p + pp) * 64 + qg * 4]);
            const int pg = p >> 2;
            #pragma unroll
            for (int i = 0; i < 8; ++i) {
                const int row = bl * 8 + i;
                const int spg = pg ^ ((row >> 3) & 3);
                float4 xv = *reinterpret_cast<const float4*>(&xs[row * PCHUNK + spg * 4]);
                const float xe[4] = {xv.x, xv.y, xv.z, xv.w};
                #pragma unroll
                for (int pp = 0; pp < 4; ++pp) {
                    const float le[4] = {lv[pp].x, lv[pp].y, lv[pp].z, lv[pp].w};
                    #pragma unroll
                    for (int j = 0; j < 4; ++j) {
                        const float s = xe[pp] + ee[j];
                        acc1[i][j] = fmaf(s,        le[j], acc1[i][j]);
                        acc2[i][j] = fmaf(fabsf(s), le[j], acc2[i][j]);
                    }
                }
            }
        }
        __syncthreads();  // WAR: next chunk overwrites LDS
    }

    float* P = Part + (size_t)blockIdx.z * B * n_out;
    #pragma unroll
    for (int i = 0; i < 8; ++i) {
        const int b = b0 + bl * 8 + i;
        float4 o;
        o.x = c1 * acc1[i][0] + c2 * acc2[i][0];
        o.y = c1 * acc1[i][1] + c2 * acc2[i][1];
        o.z = c1 * acc1[i][2] + c2 * acc2[i][2];
        o.w = c1 * acc1[i][3] + c2 * acc2[i][3];
        *reinterpret_cast<float4*>(P + (size_t)b * n_out + q) = o;
    }
}

__global__ __launch_bounds__(256) void gskan_combine_kernel(
    const float* __restrict__ Part, float* __restrict__ Y, int n, int nsplit)
{
    int i = (blockIdx.x * 256 + threadIdx.x) * 4;
    if (i >= n) return;
    float4 acc = *reinterpret_cast<const float4*>(Part + i);
    for (int s = 1; s < nsplit; ++s) {
        float4 v = *reinterpret_cast<const float4*>(Part + (size_t)s * n + i);
        acc.x += v.x; acc.y += v.y; acc.z += v.z; acc.w += v.w;
    }
    *reinterpret_cast<float4*>(Y + i) = acc;
}

extern "C" void kernel_launch(void* const* d_in, const int* in_sizes, int n_in_args,
                              void* d_out, int out_size, void* d_ws, size_t ws_size,
                              hipStream_t stream)
{
    (void)n_in_args; (void)out_size;

    const float* x = (const float*)d_in[0];

    struct LayerP { const float *Lam, *Eps, *Aw; int n_in, n_out; };
    LayerP layers[4];
    for (int i = 0; i < 4; ++i) {
        layers[i].Lam   = (const float*)d_in[1 + 3 * i];
        layers[i].Eps   = (const float*)d_in[2 + 3 * i];
        layers[i].Aw    = (const float*)d_in[3 + 3 * i];
        layers[i].n_out = in_sizes[2 + 3 * i];
        layers[i].n_in  = in_sizes[1 + 3 * i] / layers[i].n_out;
    }
    const int B = in_sizes[0] / layers[0].n_in;

    // ws layout: [Part: 16MB][yA: 2MB][yB: 2MB]
    char* ws = (char*)d_ws;
    float* Part = (float*)ws;
    float* yA   = (float*)(ws + (size_t)(16u << 20));
    float* yB   = (float*)(ws + (size_t)(18u << 20));
    const bool have_ws = ws_size >= (size_t)(20u << 20);

    const float* cur = x;
    for (int i = 0; i < 4; ++i) {
        const LayerP& ly = layers[i];
        const int nq = ly.n_out / 64;
        const int nb = B / 128;

        int nsplit = 1;
        if (have_ws) {
            nsplit = 512 / (nq * nb);               // target 512 blocks = 2/CU
            if (nsplit < 1) nsplit = 1;
            int max_split = ly.n_in / PCHUNK;
            if (nsplit > max_split) nsplit = max_split;
        }
        int p_per = ((ly.n_in + nsplit * PCHUNK - 1) / (nsplit * PCHUNK)) * PCHUNK;
        nsplit = (ly.n_in + p_per - 1) / p_per;

        float* Y = (i == 3) ? (float*)d_out : ((i % 2 == 0) ? yA : yB);
        float* dst = (nsplit == 1) ? Y : Part;

        dim3 grid(nq, nb, nsplit), block(256);
        hipLaunchKernelGGL(gskan_partial_kernel, grid, block, 0, stream,
                           cur, ly.Lam, ly.Eps, ly.Aw, dst,
                           B, ly.n_in, ly.n_out, p_per);

        if (nsplit > 1) {
            const int n = B * ly.n_out;
            dim3 cg((n / 4 + 255) / 256), cb(256);
            hipLaunchKernelGGL(gskan_combine_kernel, cg, cb, 0, stream, Part, Y, n, nsplit);
        }
        cur = Y;
    }
}